// Round 4
// baseline (1006.006 us; speedup 1.0000x reference)
//
#include <hip/hip_runtime.h>
#include <math.h>

namespace {
constexpr int B_ = 128;
constexpr int N_ = 256;
constexpr int H_ = 128;
constexpr int M_TOTAL = B_ * N_;  // 32768 nodes
}

#define AS1 __attribute__((address_space(1)))
#define AS3 __attribute__((address_space(3)))

// async 16B global->LDS. LDS dest = wave-uniform base + lane*16 (HW-defined).
__device__ __forceinline__ void gl_lds16(const float* g, float* l) {
  __builtin_amdgcn_global_load_lds((const AS1 unsigned int*)g,
                                   (AS3 unsigned int*)l, 16, 0, 0);
}

// ---------------- weight pre-transpose ----------------
// in: W [2][O][I][8]  ->  out: Wt [I*8][2][O]   (pair-major, sin/cos, out)
template<int I, int O>
__global__ __launch_bounds__(256)
void wtr_kernel(const float* __restrict__ in, float* __restrict__ out) {
  int idx = blockIdx.x * 256 + threadIdx.x;
  constexpr int TOTAL = 2 * O * I * 8;
  if (idx >= TOTAL) return;
  int g = idx & 7;
  int t = idx >> 3;
  int i = t % I;
  int t2 = t / I;
  int o = t2 % O;
  int s = t2 / O;
  out[(size_t)((i * 8 + g) * 2 + s) * O + o] = in[idx];
}

// ---------------- elementwise float4 add (combine split-K halves) ----------
__global__ __launch_bounds__(256)
void add4_kernel(const float* __restrict__ a, const float* __restrict__ b,
                 float* __restrict__ o, int n4) {
  int i = blockIdx.x * 256 + threadIdx.x;
  int stride = gridDim.x * 256;
  for (; i < n4; i += stride) {
    float4 x = ((const float4*)a)[i];
    float4 y = ((const float4*)b)[i];
    float4 r = {x.x + y.x, x.y + y.y, x.z + y.z, x.w + y.w};
    ((float4*)o)[i] = r;
  }
}

// ---------------- Fourier-KAN linear, split-K=2 ----------------
// out_half[node][o] = sum over half the inputs of
//   cos(x[n][i]*(g+1))*W0[o][i][g] + sin(..)*W1[o][i][g]
// Wt: [IN*8][2][128]. Block: 64 nodes x 128 outs, 256 thr.
// blockIdx: bit0 = K-half, rest = node tile. Chunk = 8 pairs (1 input), dbuf.
// LDS 24 KB -> 6 blocks/CU allowed; grid gives 4/CU resident (16 waves/CU).
template<int IN>
__global__ __launch_bounds__(256, 4)
void fourier4(const float* __restrict__ x,    // [M][IN]
              const float* __restrict__ Wt,   // [IN*8][2][128]
              float* __restrict__ out0,       // [M][128] partial (half 0)
              float* __restrict__ out1)       // [M][128] partial (half 1)
{
  constexpr int HP = IN * 4;        // pairs per K-half
  constexpr int CHUNKS = HP / 8;    // 32 (IN=64) or 64 (IN=128)
  __shared__ alignas(16) float wl[2][8][2][128];  // 16 KB
  __shared__ alignas(16) float fC[2][8][64];      // 4 KB
  __shared__ alignas(16) float fS[2][8][64];      // 4 KB

  const int tid = threadIdx.x;
  const int khalf = blockIdx.x & 1;
  const int node0 = (blockIdx.x >> 1) * 64;
  const int og = tid & 15;    // outs og*4..+3 and og*4+64..+67
  const int ng = tid >> 4;    // nodes ng*4..+3
  const int lane = tid & 63;
  const int wave = tid >> 6;
  const int nd = tid & 63;    // feature-staging node

  float* __restrict__ out = khalf ? out1 : out0;
  const float* wb = Wt + (size_t)khalf * HP * 256;       // 256 floats per pair
  const float* xrow = x + (size_t)(node0 + nd) * IN + khalf * (IN / 2);

  float acc[4][8];
  #pragma unroll
  for (int a = 0; a < 4; ++a)
    #pragma unroll
    for (int b = 0; b < 8; ++b) acc[a][b] = 0.f;

  // ---- prologue: chunk 0
  float xv = xrow[0];
  float xnext = (CHUNKS > 1) ? xrow[1] : 0.f;
  #pragma unroll
  for (int q = 0; q < 2; ++q) {
    int bw = wave * 2 + q;   // 8 blocks of 64 float4 cover 8 pairs x 256 floats
    gl_lds16(wb + (size_t)(bw * 64 + lane) * 4, &wl[0][0][0][0] + bw * 256);
  }
  {
    float s1, c1;
    sincosf(xv, &s1, &c1);
    float ckm = 1.f, skm = 0.f, ck = c1, sk = s1;
    #pragma unroll
    for (int g = 0; g < 8; ++g) {
      if ((g >> 1) == wave) { fC[0][g][nd] = ck; fS[0][g][nd] = sk; }
      float cn = 2.f * c1 * ck - ckm, sn = 2.f * c1 * sk - skm;
      ckm = ck; skm = sk; ck = cn; sk = sn;
    }
  }
  __syncthreads();

  int p = 0;
  for (int ic = 0; ic < CHUNKS; ++ic) {
    const int pn = p ^ 1;
    const bool more = (ic + 1 < CHUNKS);
    if (more) {
      // stage next chunk: weights (async) + features (redundant x4 waves)
      const float* wsrc = wb + (size_t)(ic + 1) * 2048;  // 8 pairs * 256 floats
      #pragma unroll
      for (int q = 0; q < 2; ++q) {
        int bw = wave * 2 + q;
        gl_lds16(wsrc + (size_t)(bw * 64 + lane) * 4,
                 &wl[pn][0][0][0] + bw * 256);
      }
      float s1, c1;
      sincosf(xnext, &s1, &c1);
      float ckm = 1.f, skm = 0.f, ck = c1, sk = s1;
      #pragma unroll
      for (int g = 0; g < 8; ++g) {
        if ((g >> 1) == wave) { fC[pn][g][nd] = ck; fS[pn][g][nd] = sk; }
        float cn = 2.f * c1 * ck - ckm, sn = 2.f * c1 * sk - skm;
        ckm = ck; skm = sk; ck = cn; sk = sn;
      }
      if (ic + 2 < CHUNKS) xnext = xrow[ic + 2];
    }
    // ---- compute on buf p: 8 pairs x (4 nodes x 8 outs x {cos,sin})
    #pragma unroll 4
    for (int j = 0; j < 8; ++j) {
      float4 fc = *(const float4*)&fC[p][j][ng * 4];
      float4 fs = *(const float4*)&fS[p][j][ng * 4];
      float4 w0a = *(const float4*)&wl[p][j][0][og * 4];
      float4 w0b = *(const float4*)&wl[p][j][0][og * 4 + 64];
      float4 w1a = *(const float4*)&wl[p][j][1][og * 4];
      float4 w1b = *(const float4*)&wl[p][j][1][og * 4 + 64];
      float fcv[4] = {fc.x, fc.y, fc.z, fc.w};
      float fsv[4] = {fs.x, fs.y, fs.z, fs.w};
      float wa0[4] = {w0a.x, w0a.y, w0a.z, w0a.w};
      float wb0[4] = {w0b.x, w0b.y, w0b.z, w0b.w};
      float wa1[4] = {w1a.x, w1a.y, w1a.z, w1a.w};
      float wb1[4] = {w1b.x, w1b.y, w1b.z, w1b.w};
      #pragma unroll
      for (int nd2 = 0; nd2 < 4; ++nd2) {
        #pragma unroll
        for (int oo = 0; oo < 4; ++oo) {
          acc[nd2][oo]     += fcv[nd2] * wa0[oo] + fsv[nd2] * wa1[oo];
          acc[nd2][4 + oo] += fcv[nd2] * wb0[oo] + fsv[nd2] * wb1[oo];
        }
      }
    }
    __syncthreads();
    p ^= 1;
  }

  #pragma unroll
  for (int nd2 = 0; nd2 < 4; ++nd2) {
    int row = node0 + ng * 4 + nd2;
    float4 ra = {acc[nd2][0], acc[nd2][1], acc[nd2][2], acc[nd2][3]};
    float4 rb = {acc[nd2][4], acc[nd2][5], acc[nd2][6], acc[nd2][7]};
    *(float4*)&out[(size_t)row * H_ + og * 4] = ra;
    *(float4*)&out[(size_t)row * H_ + og * 4 + 64] = rb;
  }
}

// ---------------- Aggregation + residual + leaky ----------------
// f = f0 + f1 fused during staging (reg load both halves, add, ds_write).
// h_out[b][m][o] = leaky( sum_k A[b][k>>2][k&3][m] * (f0+f1)[b][k>>2][o]
//                         + h_in[b][m][o] )
__global__ __launch_bounds__(256)
void agg3(const float* __restrict__ A,     // [B][N][4][N]
          const float* __restrict__ f0,    // [B][N][128] partial
          const float* __restrict__ f1,    // [B][N][128] partial
          const float* __restrict__ h_in,  // [B][N][128]
          float* __restrict__ h_out)       // [B][N][128]
{
  __shared__ alignas(16) float As[2][32][64];    // 16 KB
  __shared__ alignas(16) float fsh[2][8][128];   // 8 KB
  const int tid = threadIdx.x;
  const int b = blockIdx.x >> 2;
  const int m0 = (blockIdx.x & 3) * 64;
  const int og = tid & 15;   // outs og*4, og*4+64
  const int mg = tid >> 4;   // m rows mg*4..+3
  const int wave = tid >> 6;
  const int fr = tid >> 5;          // f row-in-chunk 0..7
  const int fc4 = (tid & 31) * 4;   // f col

  float acc[4][8];
  #pragma unroll
  for (int i = 0; i < 4; ++i)
    #pragma unroll
    for (int j = 0; j < 8; ++j) acc[i][j] = 0.f;

  const float* Ab  = A  + (size_t)b * (N_ * 4 * N_) + m0;
  const float* f0b = f0 + (size_t)b * (N_ * H_);
  const float* f1b = f1 + (size_t)b * (N_ * H_);

  // ---- prologue chunk 0
  float4 u0 = *(const float4*)(f0b + (size_t)fr * H_ + fc4);
  float4 u1 = *(const float4*)(f1b + (size_t)fr * H_ + fc4);
  #pragma unroll
  for (int q = 0; q < 2; ++q) {
    int v = q * 256 + tid;  // float4 index into [32][64]
    gl_lds16(Ab + (size_t)(v >> 4) * N_ + (v & 15) * 4,
             &As[0][0][0] + (size_t)(q * 256 + wave * 64) * 4);
  }
  {
    float4 s = {u0.x + u1.x, u0.y + u1.y, u0.z + u1.z, u0.w + u1.w};
    *(float4*)&fsh[0][fr][fc4] = s;
  }
  __syncthreads();

  int p = 0;
  for (int ch = 0; ch < 32; ++ch) {
    const int pn = p ^ 1;
    float4 v0, v1;
    if (ch + 1 < 32) {
      // issue f loads first (oldest in vmcnt FIFO), then async A staging
      v0 = *(const float4*)(f0b + (size_t)((ch + 1) * 8 + fr) * H_ + fc4);
      v1 = *(const float4*)(f1b + (size_t)((ch + 1) * 8 + fr) * H_ + fc4);
      const float* Asrc = Ab + (size_t)(ch + 1) * 32 * N_;
      #pragma unroll
      for (int q = 0; q < 2; ++q) {
        int v = q * 256 + tid;
        gl_lds16(Asrc + (size_t)(v >> 4) * N_ + (v & 15) * 4,
                 &As[pn][0][0] + (size_t)(q * 256 + wave * 64) * 4);
      }
    }
    #pragma unroll
    for (int kk = 0; kk < 32; ++kk) {
      float4 a  = *(const float4*)&As[p][kk][mg * 4];
      float4 g0 = *(const float4*)&fsh[p][kk >> 2][og * 4];
      float4 g1 = *(const float4*)&fsh[p][kk >> 2][og * 4 + 64];
      float av[4] = {a.x, a.y, a.z, a.w};
      float fo[8] = {g0.x, g0.y, g0.z, g0.w, g1.x, g1.y, g1.z, g1.w};
      #pragma unroll
      for (int mi = 0; mi < 4; ++mi)
        #pragma unroll
        for (int oi = 0; oi < 8; ++oi)
          acc[mi][oi] += av[mi] * fo[oi];
    }
    if (ch + 1 < 32) {
      float4 s = {v0.x + v1.x, v0.y + v1.y, v0.z + v1.z, v0.w + v1.w};
      *(float4*)&fsh[pn][fr][fc4] = s;
    }
    __syncthreads();
    p ^= 1;
  }

  #pragma unroll
  for (int mi = 0; mi < 4; ++mi) {
    int row = b * N_ + m0 + mg * 4 + mi;
    const float* hr = &h_in[(size_t)row * H_];
    float* ho = &h_out[(size_t)row * H_];
    float4 r0 = *(const float4*)&hr[og * 4];
    float4 r1 = *(const float4*)&hr[og * 4 + 64];
    float4 o0, o1;
    float v;
    v = acc[mi][0] + r0.x; o0.x = v >= 0.f ? v : 0.01f * v;
    v = acc[mi][1] + r0.y; o0.y = v >= 0.f ? v : 0.01f * v;
    v = acc[mi][2] + r0.z; o0.z = v >= 0.f ? v : 0.01f * v;
    v = acc[mi][3] + r0.w; o0.w = v >= 0.f ? v : 0.01f * v;
    v = acc[mi][4] + r1.x; o1.x = v >= 0.f ? v : 0.01f * v;
    v = acc[mi][5] + r1.y; o1.y = v >= 0.f ? v : 0.01f * v;
    v = acc[mi][6] + r1.z; o1.z = v >= 0.f ? v : 0.01f * v;
    v = acc[mi][7] + r1.w; o1.w = v >= 0.f ? v : 0.01f * v;
    *(float4*)&ho[og * 4] = o0;
    *(float4*)&ho[og * 4 + 64] = o1;
  }
}

// ---------------- Masked mean pool + KAN head + sigmoid ----------------
__global__ __launch_bounds__(128)
void pool_kernel(const float* __restrict__ h,     // [B][N][128]
                 const int* __restrict__ mol,     // [B]
                 const float* __restrict__ Wout,  // [2][1][128][1]
                 const float* __restrict__ bout,  // [1][1]
                 float* __restrict__ out)         // [B]
{
  __shared__ float red[128];
  const int b = blockIdx.x;
  const int t = threadIdx.x;
  const int ms = mol[b];
  const float* hb = h + (size_t)b * N_ * H_;
  float sum = 0.f;
  for (int n = 0; n < ms; ++n) sum += hb[(size_t)n * H_ + t];
  float y = sum / (float)ms;
  float s1, c1;
  sincosf(y, &s1, &c1);
  red[t] = c1 * Wout[t] + s1 * Wout[H_ + t];
  __syncthreads();
  for (int sft = 64; sft > 0; sft >>= 1) {
    if (t < sft) red[t] += red[t + sft];
    __syncthreads();
  }
  if (t == 0) {
    float z = red[0] + bout[0];
    out[b] = 1.f / (1.f + expf(-z));
  }
}

extern "C" void kernel_launch(void* const* d_in, const int* in_sizes, int n_in,
                              void* d_out, int out_size, void* d_ws, size_t ws_size,
                              hipStream_t stream) {
  const float* V    = (const float*)d_in[0];
  const float* A    = (const float*)d_in[1];
  const int*   mol  = (const int*)d_in[2];
  const float* Win  = (const float*)d_in[3];
  const float* Wg   = (const float*)d_in[4];
  const float* Wout = (const float*)d_in[5];
  const float* bout = (const float*)d_in[6];
  float* out = (float*)d_out;

  const size_t BUF = (size_t)M_TOTAL * H_;           // 4M floats = 16 MB
  float* h     = (float*)d_ws;
  float* h2    = h  + BUF;
  float* f0    = h2 + BUF;
  float* f1    = f0 + BUF;
  float* wt_in = f1 + BUF;                           // [512][2][128]
  float* wt_g0 = wt_in + 512 * 2 * H_;               // [1024][2][128]
  float* wt_g1 = wt_g0 + 1024 * 2 * H_;

  wtr_kernel<64, 128><<<(2 * 128 * 64 * 8) / 256, 256, 0, stream>>>(Win, wt_in);
  wtr_kernel<128, 128><<<(2 * 128 * 128 * 8) / 256, 256, 0, stream>>>(Wg, wt_g0);
  wtr_kernel<128, 128><<<(2 * 128 * 128 * 8) / 256, 256, 0, stream>>>(
      Wg + (size_t)2 * 128 * 128 * 8, wt_g1);

  // layer 0: split-K fourier into f0/f1, combine into h
  fourier4<64><<<(M_TOTAL / 64) * 2, 256, 0, stream>>>(V, wt_in, f0, f1);
  add4_kernel<<<2048, 256, 0, stream>>>(f0, f1, h, (int)(BUF / 4));

  float* hc = h;
  float* hn = h2;
  const float* wt_g[2] = {wt_g0, wt_g1};
  for (int l = 0; l < 2; ++l) {
    fourier4<128><<<(M_TOTAL / 64) * 2, 256, 0, stream>>>(hc, wt_g[l], f0, f1);
    agg3<<<B_ * 4, 256, 0, stream>>>(A, f0, f1, hc, hn);
    float* tmp = hc; hc = hn; hn = tmp;
  }

  pool_kernel<<<B_, 128, 0, stream>>>(hc, mol, Wout, bout, out);
}